// Round 3
// baseline (265.705 us; speedup 1.0000x reference)
//
#include <hip/hip_runtime.h>
#include <hip/hip_bf16.h>

#define NN 8192
#define DD 256
#define BM 128

typedef __bf16 bf16x8 __attribute__((ext_vector_type(8)));
typedef float f32x4 __attribute__((ext_vector_type(4)));

// ---------------- prep: rnorm + bf16 hi/lo split ----------------
__global__ __launch_bounds__(256) void prep_kernel(
    const float* __restrict__ Z,
    __hip_bfloat16* __restrict__ Zhi,
    __hip_bfloat16* __restrict__ Zlo,
    float* __restrict__ rnorm) {
  const int gtid = blockIdx.x * 256 + threadIdx.x;
  const int row  = gtid >> 6;          // one wave per row
  const int lane = threadIdx.x & 63;
  if (row >= NN) return;

  const float4 v = reinterpret_cast<const float4*>(Z + (size_t)row * DD)[lane];
  float ss = v.x * v.x + v.y * v.y + v.z * v.z + v.w * v.w;
#pragma unroll
  for (int off = 32; off > 0; off >>= 1) ss += __shfl_xor(ss, off);
  if (lane == 0) rnorm[row] = 1.0f / fmaxf(sqrtf(ss), 1e-8f);

  float f[4] = {v.x, v.y, v.z, v.w};
  unsigned short hi[4], lo[4];
#pragma unroll
  for (int i = 0; i < 4; ++i) {
    __hip_bfloat16 h = __float2bfloat16(f[i]);
    float hf = __bfloat162float(h);
    __hip_bfloat16 l = __float2bfloat16(f[i] - hf);
    hi[i] = *reinterpret_cast<unsigned short*>(&h);
    lo[i] = *reinterpret_cast<unsigned short*>(&l);
  }
  ushort4 hv = make_ushort4(hi[0], hi[1], hi[2], hi[3]);
  ushort4 lv = make_ushort4(lo[0], lo[1], lo[2], lo[3]);
  reinterpret_cast<ushort4*>(Zhi + (size_t)row * DD)[lane] = hv;
  reinterpret_cast<ushort4*>(Zlo + (size_t)row * DD)[lane] = lv;
}

// ------- upper-tri Gram GEMM, barrier-free, fragments direct from L2/L3 -----
__global__ __launch_bounds__(256) void gram_kernel(
    const __hip_bfloat16* __restrict__ Zhi,
    const __hip_bfloat16* __restrict__ Zlo,
    const float* __restrict__ rnorm,
    const int* __restrict__ batch,
    float* __restrict__ outA,
    float* __restrict__ outS) {
  const int tid  = threadIdx.x;
  const int lane = tid & 63;
  const int wid  = tid >> 6;
  const int wr   = wid >> 1;   // 2x2 wave grid, each wave 64x64
  const int wc   = wid & 1;
  const int lr   = lane >> 4;  // 0..3  (k-chunk / row-quad group)
  const int lc   = lane & 15;  // 0..15 (row/col within fragment)

  // triangular decode: idx -> (brow <= bcol)
  const int idx = blockIdx.x;
  int bcol = (int)((sqrtf(8.0f * (float)idx + 1.0f) - 1.0f) * 0.5f);
  while ((bcol + 1) * (bcol + 2) / 2 <= idx) ++bcol;
  while (bcol * (bcol + 1) / 2 > idx) --bcol;
  const int brow = idx - bcol * (bcol + 1) / 2;
  const int row0 = brow * BM, col0 = bcol * BM;

  // fragment base pointers (verified 16x16x32 A/B layout: row = lc, k = lr*8+j)
  const int ra = row0 + wr * 64 + lc;
  const int rb = col0 + wc * 64 + lc;
  const __hip_bfloat16* pAh = Zhi + (size_t)ra * DD + lr * 8;
  const __hip_bfloat16* pAl = Zlo + (size_t)ra * DD + lr * 8;
  const __hip_bfloat16* pBh = Zhi + (size_t)rb * DD + lr * 8;
  const __hip_bfloat16* pBl = Zlo + (size_t)rb * DD + lr * 8;

  f32x4 acc[4][4] = {};

  for (int kt = 0; kt < DD / 32; ++kt) {
    const int ko = kt * 32;
    bf16x8 ah[4], al[4], bh[4], bl[4];
#pragma unroll
    for (int m = 0; m < 4; ++m) {
      ah[m] = *reinterpret_cast<const bf16x8*>(pAh + (size_t)m * 16 * DD + ko);
      al[m] = *reinterpret_cast<const bf16x8*>(pAl + (size_t)m * 16 * DD + ko);
    }
#pragma unroll
    for (int n = 0; n < 4; ++n) {
      bh[n] = *reinterpret_cast<const bf16x8*>(pBh + (size_t)n * 16 * DD + ko);
      bl[n] = *reinterpret_cast<const bf16x8*>(pBl + (size_t)n * 16 * DD + ko);
    }
#pragma unroll
    for (int m = 0; m < 4; ++m) {
#pragma unroll
      for (int n = 0; n < 4; ++n) {
        acc[m][n] = __builtin_amdgcn_mfma_f32_16x16x32_bf16(ah[m], bh[n], acc[m][n], 0, 0, 0);
        acc[m][n] = __builtin_amdgcn_mfma_f32_16x16x32_bf16(ah[m], bl[n], acc[m][n], 0, 0, 0);
        acc[m][n] = __builtin_amdgcn_mfma_f32_16x16x32_bf16(al[m], bh[n], acc[m][n], 0, 0, 0);
      }
    }
  }

  // per-thread norm/batch values straight from L2 (no LDS, no barriers)
  float rnB_[4]; int btB_[4];
#pragma unroll
  for (int n = 0; n < 4; ++n) {
    const int cg = col0 + wc * 64 + n * 16 + lc;
    rnB_[n] = rnorm[cg];
    btB_[n] = batch[cg];
  }
  float rnA_[4][4]; int btA_[4][4];
#pragma unroll
  for (int m = 0; m < 4; ++m)
#pragma unroll
    for (int j = 0; j < 4; ++j) {
      const int rg = row0 + wr * 64 + m * 16 + lr * 4 + j;
      rnA_[m][j] = rnorm[rg];
      btA_[m][j] = batch[rg];
    }

  const bool mirror = (brow != bcol);

  // epilogue: one sigmoid per element, reused by direct (scalar) and
  // mirrored (native float4: acc quad j = 4 consecutive mirror columns) writes
#pragma unroll
  for (int m = 0; m < 4; ++m) {
    const int rg0 = row0 + wr * 64 + m * 16 + lr * 4;
#pragma unroll
    for (int n = 0; n < 4; ++n) {
      const int cg  = col0 + wc * 64 + n * 16 + lc;
      const float rb_ = rnB_[n];
      const int   bb  = btB_[n];
      f32x4 a4, s4;
#pragma unroll
      for (int j = 0; j < 4; ++j) {
        const float g = acc[m][n][j];
        a4[j] = __builtin_amdgcn_rcpf(1.0f + __expf(-g));
        s4[j] = (btA_[m][j] == bb) ? g * rnA_[m][j] * rb_ : 0.0f;
        const size_t o = (size_t)(rg0 + j) * NN + cg;
        outA[o] = a4[j];
        outS[o] = s4[j];
      }
      if (mirror) {
        const size_t o = (size_t)cg * NN + rg0;   // rg0 % 4 == 0 -> 16B aligned
        *reinterpret_cast<f32x4*>(outA + o) = a4;
        *reinterpret_cast<f32x4*>(outS + o) = s4;
      }
    }
  }
}

extern "C" void kernel_launch(void* const* d_in, const int* in_sizes, int n_in,
                              void* d_out, int out_size, void* d_ws, size_t ws_size,
                              hipStream_t stream) {
  const float* Z     = (const float*)d_in[0];
  const int*   batch = (const int*)d_in[1];
  float* out = (float*)d_out;

  __hip_bfloat16* Zhi = (__hip_bfloat16*)d_ws;
  __hip_bfloat16* Zlo = Zhi + (size_t)NN * DD;
  float* rnorm = (float*)(Zlo + (size_t)NN * DD);

  prep_kernel<<<NN / 4, 256, 0, stream>>>(Z, Zhi, Zlo, rnorm);

  const int nb = NN / BM;                 // 64
  const int nblocks = nb * (nb + 1) / 2;  // 2080
  gram_kernel<<<dim3(nblocks), 256, 0, stream>>>(Zhi, Zlo, rnorm, batch, out,
                                                 out + (size_t)NN * NN);
}

// Round 4
// 156.733 us; speedup vs baseline: 1.6953x; 1.6953x over previous
//
#include <hip/hip_runtime.h>
#include <hip/hip_bf16.h>

#define NN 8192
#define DD 256
#define BM 128
#define BN 128
#define BK 32

typedef __bf16 bf16x8 __attribute__((ext_vector_type(8)));
typedef float f32x4 __attribute__((ext_vector_type(4)));

__device__ inline void gload_lds16(const void* g, void* l) {
  __builtin_amdgcn_global_load_lds(
      (const __attribute__((address_space(1))) void*)g,
      (__attribute__((address_space(3))) void*)l, 16, 0, 0);
}

// ---------------- prep: rnorm + bf16 hi/lo split ----------------
__global__ __launch_bounds__(256) void prep_kernel(
    const float* __restrict__ Z,
    __hip_bfloat16* __restrict__ Zhi,
    __hip_bfloat16* __restrict__ Zlo,
    float* __restrict__ rnorm) {
  const int gtid = blockIdx.x * 256 + threadIdx.x;
  const int row  = gtid >> 6;          // one wave per row
  const int lane = threadIdx.x & 63;
  if (row >= NN) return;

  const float4 v = reinterpret_cast<const float4*>(Z + (size_t)row * DD)[lane];
  float ss = v.x * v.x + v.y * v.y + v.z * v.z + v.w * v.w;
#pragma unroll
  for (int off = 32; off > 0; off >>= 1) ss += __shfl_xor(ss, off);
  if (lane == 0) rnorm[row] = 1.0f / fmaxf(sqrtf(ss), 1e-8f);

  float f[4] = {v.x, v.y, v.z, v.w};
  unsigned short hi[4], lo[4];
#pragma unroll
  for (int i = 0; i < 4; ++i) {
    __hip_bfloat16 h = __float2bfloat16(f[i]);
    float hf = __bfloat162float(h);
    __hip_bfloat16 l = __float2bfloat16(f[i] - hf);
    hi[i] = *reinterpret_cast<unsigned short*>(&h);
    lo[i] = *reinterpret_cast<unsigned short*>(&l);
  }
  ushort4 hv = make_ushort4(hi[0], hi[1], hi[2], hi[3]);
  ushort4 lv = make_ushort4(lo[0], lo[1], lo[2], lo[3]);
  reinterpret_cast<ushort4*>(Zhi + (size_t)row * DD)[lane] = hv;
  reinterpret_cast<ushort4*>(Zlo + (size_t)row * DD)[lane] = lv;
}

// LDS: K-loop staging tiles union'd with the f32 transpose buffer
struct __attribute__((aligned(16))) SharedT {
  union {
    struct {
      __hip_bfloat16 Ah[BM * BK];
      __hip_bfloat16 Al[BM * BK];
      __hip_bfloat16 Bh[BN * BK];
      __hip_bfloat16 Bl[BN * BK];
    } t;
    float tbuf[BM][BN + 1];   // pad+1: row AND column access conflict-free (b32)
  };
};

// ------ upper-tri Gram GEMM + cooperative coalesced dual epilogue -----------
__global__ __launch_bounds__(256, 2) void gram_kernel(
    const __hip_bfloat16* __restrict__ Zhi,
    const __hip_bfloat16* __restrict__ Zlo,
    const float* __restrict__ rnorm,
    const int* __restrict__ batch,
    float* __restrict__ outA,
    float* __restrict__ outS) {
  __shared__ SharedT sh;
  __shared__ float sRnA[BM];
  __shared__ float sRnB[BN];
  __shared__ int   sBtA[BM];
  __shared__ int   sBtB[BN];

  const int tid  = threadIdx.x;
  const int lane = tid & 63;
  const int wid  = tid >> 6;
  const int wr   = wid >> 1;   // 2x2 wave grid, each wave 64x64
  const int wc   = wid & 1;

  // triangular decode: idx -> (brow <= bcol)
  const int idx = blockIdx.x;
  int bcol = (int)((sqrtf(8.0f * (float)idx + 1.0f) - 1.0f) * 0.5f);
  while ((bcol + 1) * (bcol + 2) / 2 <= idx) ++bcol;
  while (bcol * (bcol + 1) / 2 > idx) --bcol;
  const int brow = idx - bcol * (bcol + 1) / 2;
  const int row0 = brow * BM, col0 = bcol * BN;

  if (tid < 128) {
    sRnA[tid] = rnorm[row0 + tid];
    sBtA[tid] = batch[row0 + tid];
  } else {
    const int t = tid - 128;
    sRnB[t] = rnorm[col0 + t];
    sBtB[t] = batch[col0 + t];
  }

  f32x4 acc[4][4] = {};

  const int lr = lane >> 4;   // 0..3  (k-chunk)
  const int lc = lane & 15;   // 0..15 (row within fragment)

  for (int kt = 0; kt < DD / BK; ++kt) {
    const int k0 = kt * BK;
    // stage 4 tiles of 128x32 bf16, XOR-swizzled on the GLOBAL side
    // (LDS dest linear; involution ch ^= (r>>1)&3 applied again on read)
#pragma unroll
    for (int c = 0; c < 2; ++c) {
      const int ci  = c * 256 + tid;            // 16B-chunk index [0,512)
      const int r   = ci >> 2;                  // tile-local row
      const int ch  = ci & 3;
      const int chg = ch ^ ((r >> 1) & 3);      // swizzled source chunk
      const int base = (c * 256 + wid * 64) * 16;  // wave-uniform LDS byte base
      const size_t ga = (size_t)(row0 + r) * DD + k0 + chg * 8;
      const size_t gb = (size_t)(col0 + r) * DD + k0 + chg * 8;
      gload_lds16(Zhi + ga, (char*)sh.t.Ah + base);
      gload_lds16(Zlo + ga, (char*)sh.t.Al + base);
      gload_lds16(Zhi + gb, (char*)sh.t.Bh + base);
      gload_lds16(Zlo + gb, (char*)sh.t.Bl + base);
    }
    __syncthreads();   // drains vmcnt before any wave reads LDS

    bf16x8 ah[4], al[4], bh[4], bl[4];
#pragma unroll
    for (int m = 0; m < 4; ++m) {
      const int rA = wr * 64 + m * 16 + lc;
      const int off = rA * BK + ((lr ^ ((rA >> 1) & 3)) << 3);
      ah[m] = *reinterpret_cast<const bf16x8*>(&sh.t.Ah[off]);
      al[m] = *reinterpret_cast<const bf16x8*>(&sh.t.Al[off]);
    }
#pragma unroll
    for (int n = 0; n < 4; ++n) {
      const int rB = wc * 64 + n * 16 + lc;
      const int off = rB * BK + ((lr ^ ((rB >> 1) & 3)) << 3);
      bh[n] = *reinterpret_cast<const bf16x8*>(&sh.t.Bh[off]);
      bl[n] = *reinterpret_cast<const bf16x8*>(&sh.t.Bl[off]);
    }
#pragma unroll
    for (int m = 0; m < 4; ++m) {
#pragma unroll
      for (int n = 0; n < 4; ++n) {
        acc[m][n] = __builtin_amdgcn_mfma_f32_16x16x32_bf16(ah[m], bh[n], acc[m][n], 0, 0, 0);
        acc[m][n] = __builtin_amdgcn_mfma_f32_16x16x32_bf16(ah[m], bl[n], acc[m][n], 0, 0, 0);
        acc[m][n] = __builtin_amdgcn_mfma_f32_16x16x32_bf16(al[m], bh[n], acc[m][n], 0, 0, 0);
      }
    }
    __syncthreads();
  }

  // dump raw g into tbuf (staging tiles are dead); 4-way conflict, ~1us total
#pragma unroll
  for (int m = 0; m < 4; ++m)
#pragma unroll
    for (int n = 0; n < 4; ++n)
#pragma unroll
      for (int j = 0; j < 4; ++j) {
        const int rowl = wr * 64 + m * 16 + lr * 4 + j;
        const int coll = wc * 64 + n * 16 + lc;
        sh.tbuf[rowl][coll] = acc[m][n][j];
      }
  __syncthreads();

  // phase A: direct tile, cooperative. 64 consecutive lanes -> 256B
  // contiguous per store instruction; tbuf row read conflict-free (pad 129).
#pragma unroll 4
  for (int i = 0; i < (BM * BN) / 256; ++i) {
    const int e = i * 256 + tid;
    const int r = e >> 7;        // 0..127
    const int c = e & 127;
    const float g = sh.tbuf[r][c];
    const float a = __builtin_amdgcn_rcpf(1.0f + __expf(-g));
    const float s = (sBtA[r] == sBtB[c]) ? g * sRnA[r] * sRnB[c] : 0.0f;
    const size_t o = (size_t)(row0 + r) * NN + (col0 + c);
    outA[o] = a;
    outS[o] = s;
  }

  // phase B: mirrored tile, cooperative transposed read (column read
  // conflict-free via pad 129), 256B contiguous stores.
  if (brow != bcol) {
#pragma unroll 4
    for (int i = 0; i < (BM * BN) / 256; ++i) {
      const int e  = i * 256 + tid;
      const int rt = e >> 7;     // transposed row  = original col
      const int ct = e & 127;    // transposed col  = original row
      const float g = sh.tbuf[ct][rt];
      const float a = __builtin_amdgcn_rcpf(1.0f + __expf(-g));
      const float s = (sBtB[rt] == sBtA[ct]) ? g * sRnB[rt] * sRnA[ct] : 0.0f;
      const size_t o = (size_t)(col0 + rt) * NN + (row0 + ct);
      outA[o] = a;
      outS[o] = s;
    }
  }
}

extern "C" void kernel_launch(void* const* d_in, const int* in_sizes, int n_in,
                              void* d_out, int out_size, void* d_ws, size_t ws_size,
                              hipStream_t stream) {
  const float* Z     = (const float*)d_in[0];
  const int*   batch = (const int*)d_in[1];
  float* out = (float*)d_out;

  __hip_bfloat16* Zhi = (__hip_bfloat16*)d_ws;
  __hip_bfloat16* Zlo = Zhi + (size_t)NN * DD;
  float* rnorm = (float*)(Zlo + (size_t)NN * DD);

  prep_kernel<<<NN / 4, 256, 0, stream>>>(Z, Zhi, Zlo, rnorm);

  const int nb = NN / BM;                 // 64
  const int nblocks = nb * (nb + 1) / 2;  // 2080
  gram_kernel<<<dim3(nblocks), 256, 0, stream>>>(Zhi, Zlo, rnorm, batch, out,
                                                 out + (size_t)NN * NN);
}

// Round 5
// 149.597 us; speedup vs baseline: 1.7761x; 1.0477x over previous
//
#include <hip/hip_runtime.h>
#include <hip/hip_bf16.h>

#define NN 8192
#define DD 256
#define BM 128
#define BN 128
#define BK 32

typedef __bf16 bf16x8 __attribute__((ext_vector_type(8)));
typedef float f32x4 __attribute__((ext_vector_type(4)));

__device__ inline void gload_lds16(const void* g, void* l) {
  __builtin_amdgcn_global_load_lds(
      (const __attribute__((address_space(1))) void*)g,
      (__attribute__((address_space(3))) void*)l, 16, 0, 0);
}

// ---------------- prep: rnorm + bf16 hi/lo split ----------------
__global__ __launch_bounds__(256) void prep_kernel(
    const float* __restrict__ Z,
    __hip_bfloat16* __restrict__ Zhi,
    __hip_bfloat16* __restrict__ Zlo,
    float* __restrict__ rnorm) {
  const int gtid = blockIdx.x * 256 + threadIdx.x;
  const int row  = gtid >> 6;          // one wave per row
  const int lane = threadIdx.x & 63;
  if (row >= NN) return;

  const float4 v = reinterpret_cast<const float4*>(Z + (size_t)row * DD)[lane];
  float ss = v.x * v.x + v.y * v.y + v.z * v.z + v.w * v.w;
#pragma unroll
  for (int off = 32; off > 0; off >>= 1) ss += __shfl_xor(ss, off);
  if (lane == 0) rnorm[row] = 1.0f / fmaxf(sqrtf(ss), 1e-8f);

  float f[4] = {v.x, v.y, v.z, v.w};
  unsigned short hi[4], lo[4];
#pragma unroll
  for (int i = 0; i < 4; ++i) {
    __hip_bfloat16 h = __float2bfloat16(f[i]);
    float hf = __bfloat162float(h);
    __hip_bfloat16 l = __float2bfloat16(f[i] - hf);
    hi[i] = *reinterpret_cast<unsigned short*>(&h);
    lo[i] = *reinterpret_cast<unsigned short*>(&l);
  }
  ushort4 hv = make_ushort4(hi[0], hi[1], hi[2], hi[3]);
  ushort4 lv = make_ushort4(lo[0], lo[1], lo[2], lo[3]);
  reinterpret_cast<ushort4*>(Zhi + (size_t)row * DD)[lane] = hv;
  reinterpret_cast<ushort4*>(Zlo + (size_t)row * DD)[lane] = lv;
}

// LDS: K-loop staging tiles union'd with the QUARTER f32 transpose buffer
struct __attribute__((aligned(16))) SharedT {
  union {
    struct {
      __hip_bfloat16 Ah[BM * BK];
      __hip_bfloat16 Al[BM * BK];
      __hip_bfloat16 Bh[BN * BK];
      __hip_bfloat16 Bl[BN * BK];
    } t;                        // 32 KB
    float tbuf[32][BN + 1];     // 16.5 KB quarter tile (rows q*32..q*32+31)
  };
};

// ------ upper-tri Gram GEMM + quartered cooperative dual epilogue -----------
__global__ __launch_bounds__(256, 3) void gram_kernel(
    const __hip_bfloat16* __restrict__ Zhi,
    const __hip_bfloat16* __restrict__ Zlo,
    const float* __restrict__ rnorm,
    const int* __restrict__ batch,
    float* __restrict__ outA,
    float* __restrict__ outS) {
  __shared__ SharedT sh;
  __shared__ float sRnA[BM];
  __shared__ float sRnB[BN];
  __shared__ int   sBtA[BM];
  __shared__ int   sBtB[BN];

  const int tid  = threadIdx.x;
  const int lane = tid & 63;
  const int wid  = tid >> 6;
  const int wr   = wid >> 1;   // 2x2 wave grid, each wave 64x64
  const int wc   = wid & 1;

  // XCD-aware swizzle (2080 % 8 == 0 -> bijective)
  const int nb  = NN / BM;                 // 64
  const int nwg = nb * (nb + 1) / 2;       // 2080
  const int bid = blockIdx.x;
  const int idx = (bid & 7) * (nwg >> 3) + (bid >> 3);

  // triangular decode: idx -> (brow <= bcol)
  int bcol = (int)((sqrtf(8.0f * (float)idx + 1.0f) - 1.0f) * 0.5f);
  while ((bcol + 1) * (bcol + 2) / 2 <= idx) ++bcol;
  while (bcol * (bcol + 1) / 2 > idx) --bcol;
  const int brow = idx - bcol * (bcol + 1) / 2;
  const int row0 = brow * BM, col0 = bcol * BN;

  if (tid < 128) {
    sRnA[tid] = rnorm[row0 + tid];
    sBtA[tid] = batch[row0 + tid];
  } else {
    const int t = tid - 128;
    sRnB[t] = rnorm[col0 + t];
    sBtB[t] = batch[col0 + t];
  }

  f32x4 acc[4][4] = {};

  const int lr = lane >> 4;   // 0..3  (k-chunk)
  const int lc = lane & 15;   // 0..15 (row within fragment)

  for (int kt = 0; kt < DD / BK; ++kt) {
    const int k0 = kt * BK;
    // stage 4 tiles of 128x32 bf16, XOR-swizzled on the GLOBAL side
    // (LDS dest linear; involution ch ^= (r>>1)&3 applied again on read)
#pragma unroll
    for (int c = 0; c < 2; ++c) {
      const int ci  = c * 256 + tid;            // 16B-chunk index [0,512)
      const int r   = ci >> 2;                  // tile-local row
      const int ch  = ci & 3;
      const int chg = ch ^ ((r >> 1) & 3);      // swizzled source chunk
      const int base = (c * 256 + wid * 64) * 16;  // wave-uniform LDS byte base
      const size_t ga = (size_t)(row0 + r) * DD + k0 + chg * 8;
      const size_t gb = (size_t)(col0 + r) * DD + k0 + chg * 8;
      gload_lds16(Zhi + ga, (char*)sh.t.Ah + base);
      gload_lds16(Zlo + ga, (char*)sh.t.Al + base);
      gload_lds16(Zhi + gb, (char*)sh.t.Bh + base);
      gload_lds16(Zlo + gb, (char*)sh.t.Bl + base);
    }
    __syncthreads();   // drains vmcnt before any wave reads LDS

    // fragment-staged MFMA: peak live = fa+fb+ft = 48 VGPR (fits 3 blocks/CU)
    bf16x8 fa[4], fb[4], ft[4];
#pragma unroll
    for (int m = 0; m < 4; ++m) {
      const int rA = wr * 64 + m * 16 + lc;
      const int off = rA * BK + ((lr ^ ((rA >> 1) & 3)) << 3);
      fa[m] = *reinterpret_cast<const bf16x8*>(&sh.t.Ah[off]);
    }
#pragma unroll
    for (int n = 0; n < 4; ++n) {
      const int rB = wc * 64 + n * 16 + lc;
      const int off = rB * BK + ((lr ^ ((rB >> 1) & 3)) << 3);
      fb[n] = *reinterpret_cast<const bf16x8*>(&sh.t.Bh[off]);
    }
#pragma unroll
    for (int m = 0; m < 4; ++m)
#pragma unroll
      for (int n = 0; n < 4; ++n)
        acc[m][n] = __builtin_amdgcn_mfma_f32_16x16x32_bf16(fa[m], fb[n], acc[m][n], 0, 0, 0);
    // lo_i * hi_j
#pragma unroll
    for (int m = 0; m < 4; ++m) {
      const int rA = wr * 64 + m * 16 + lc;
      const int off = rA * BK + ((lr ^ ((rA >> 1) & 3)) << 3);
      ft[m] = *reinterpret_cast<const bf16x8*>(&sh.t.Al[off]);
    }
#pragma unroll
    for (int m = 0; m < 4; ++m)
#pragma unroll
      for (int n = 0; n < 4; ++n)
        acc[m][n] = __builtin_amdgcn_mfma_f32_16x16x32_bf16(ft[m], fb[n], acc[m][n], 0, 0, 0);
    // hi_i * lo_j (bh dead -> overwrite fb with Bl)
#pragma unroll
    for (int n = 0; n < 4; ++n) {
      const int rB = wc * 64 + n * 16 + lc;
      const int off = rB * BK + ((lr ^ ((rB >> 1) & 3)) << 3);
      fb[n] = *reinterpret_cast<const bf16x8*>(&sh.t.Bl[off]);
    }
#pragma unroll
    for (int m = 0; m < 4; ++m)
#pragma unroll
      for (int n = 0; n < 4; ++n)
        acc[m][n] = __builtin_amdgcn_mfma_f32_16x16x32_bf16(fa[m], fb[n], acc[m][n], 0, 0, 0);
    __syncthreads();
  }

  const bool mirror = (brow != bcol);

  // quartered epilogue: rows [q*32, q*32+32) per pass
  for (int q = 0; q < 4; ++q) {
    __syncthreads();   // tbuf free (staging dead at q=0; stores done after)
    if (wr == (q >> 1)) {        // 2 of 4 waves dump this quarter
      const int mbase = (q & 1) * 2;
#pragma unroll
      for (int mm = 0; mm < 2; ++mm) {
        const int m = mbase + mm;
#pragma unroll
        for (int n = 0; n < 4; ++n)
#pragma unroll
          for (int j = 0; j < 4; ++j)
            sh.tbuf[mm * 16 + lr * 4 + j][wc * 64 + n * 16 + lc] = acc[m][n][j];
      }
    }
    __syncthreads();

    // phase A: direct rows, 256B-contiguous stores, 2-way LDS reads (free)
#pragma unroll 4
    for (int i = 0; i < 16; ++i) {
      const int e = i * 256 + tid;
      const int r = e >> 7;          // 0..31
      const int c = e & 127;
      const int rg = q * 32 + r;
      const float g = sh.tbuf[r][c];
      const float a = __builtin_amdgcn_rcpf(1.0f + __expf(-g));
      const float s = (sBtA[rg] == sBtB[c]) ? g * sRnA[rg] * sRnB[c] : 0.0f;
      const size_t o = (size_t)(row0 + rg) * NN + (col0 + c);
      outA[o] = a;
      outS[o] = s;
    }

    // phase B: mirrored cols, 128B-contiguous per 32-lane group
    if (mirror) {
#pragma unroll 4
      for (int i = 0; i < 16; ++i) {
        const int e  = i * 256 + tid;
        const int rt = e >> 5;       // 0..127 mirror row (orig col)
        const int ct = e & 31;       // 0..31  orig row within quarter
        const int rg = q * 32 + ct;
        const float g = sh.tbuf[ct][rt];
        const float a = __builtin_amdgcn_rcpf(1.0f + __expf(-g));
        const float s = (sBtB[rt] == sBtA[rg]) ? g * sRnB[rt] * sRnA[rg] : 0.0f;
        const size_t o = (size_t)(col0 + rt) * NN + (row0 + rg);
        outA[o] = a;
        outS[o] = s;
      }
    }
  }
}

extern "C" void kernel_launch(void* const* d_in, const int* in_sizes, int n_in,
                              void* d_out, int out_size, void* d_ws, size_t ws_size,
                              hipStream_t stream) {
  const float* Z     = (const float*)d_in[0];
  const int*   batch = (const int*)d_in[1];
  float* out = (float*)d_out;

  __hip_bfloat16* Zhi = (__hip_bfloat16*)d_ws;
  __hip_bfloat16* Zlo = Zhi + (size_t)NN * DD;
  float* rnorm = (float*)(Zlo + (size_t)NN * DD);

  prep_kernel<<<NN / 4, 256, 0, stream>>>(Z, Zhi, Zlo, rnorm);

  const int nb = NN / BM;                 // 64
  const int nblocks = nb * (nb + 1) / 2;  // 2080
  gram_kernel<<<dim3(nblocks), 256, 0, stream>>>(Zhi, Zlo, rnorm, batch, out,
                                                 out + (size_t)NN * NN);
}